// Round 1
// baseline (2154.967 us; speedup 1.0000x reference)
//
#include <hip/hip_runtime.h>
#include <hip/hip_bf16.h>

#define DEV __device__ __forceinline__

typedef __attribute__((ext_vector_type(8))) short bf16x8;
typedef __attribute__((ext_vector_type(4))) float f32x4;

// ---------------------------------------------------------------- helpers
DEV unsigned short bfbits(float x) {
    __hip_bfloat16 b = __float2bfloat16(x);
    return __builtin_bit_cast(unsigned short, b);
}

DEV void gl2lds16(const void* g, void* l) {
    __builtin_amdgcn_global_load_lds(
        (const __attribute__((address_space(1))) void*)g,
        (__attribute__((address_space(3))) void*)l,
        16, 0, 0);
}

DEV void stC(float* p, float v) { *p = v; }
DEV void stC(__hip_bfloat16* p, float v) { *p = __float2bfloat16(v); }

// ---------------------------------------------------------------- fp32 -> bf16 convert
__global__ __launch_bounds__(256) void cvt_bf16(const float* __restrict__ in,
                                                unsigned short* __restrict__ out, int n) {
    int i = (blockIdx.x * 256 + threadIdx.x) * 4;
    if (i >= n) return;
    float4 f = *(const float4*)(in + i);
    ushort4 u;
    u.x = bfbits(f.x); u.y = bfbits(f.y); u.z = bfbits(f.z); u.w = bfbits(f.w);
    *(ushort4*)(out + i) = u;
}

// ---------------------------------------------------------------- bf16 GEMM: C[M][N] = A[M][K] @ B[N][K]^T + bias
// m97 structure: 128x128 tile, BK=32, 4 waves, 4x4 MFMA tiles/wave, global_load_lds w=16
template <typename OutT>
__global__ __launch_bounds__(256) void gemm_bt(const __hip_bfloat16* __restrict__ A,
                                               const __hip_bfloat16* __restrict__ B,
                                               const float* __restrict__ bias,
                                               OutT* __restrict__ C,
                                               int M, int N, int K) {
    __shared__ __align__(16) unsigned short As[128 * 32];
    __shared__ __align__(16) unsigned short Bs[128 * 32];
    const int t = threadIdx.x;
    const int wave = t >> 6, lane = t & 63;
    const int quad = lane >> 4, l16 = lane & 15;
    const int m0 = blockIdx.y * 128, n0 = blockIdx.x * 128;
    const int wm = (wave & 1) * 64, wn = (wave >> 1) * 64;
    const int r0 = t >> 2;           // staging row 0..63
    const int c0 = (t & 3) * 8;      // staging col (8 bf16 = 16B)
    const unsigned short* Au = (const unsigned short*)A;
    const unsigned short* Bu = (const unsigned short*)B;

    f32x4 acc[4][4] = {};
    for (int k0 = 0; k0 < K; k0 += 32) {
        gl2lds16(Au + (size_t)(m0 + r0) * K + k0 + c0,      As + t * 8);
        gl2lds16(Au + (size_t)(m0 + 64 + r0) * K + k0 + c0, As + 2048 + t * 8);
        gl2lds16(Bu + (size_t)(n0 + r0) * K + k0 + c0,      Bs + t * 8);
        gl2lds16(Bu + (size_t)(n0 + 64 + r0) * K + k0 + c0, Bs + 2048 + t * 8);
        __syncthreads();
        bf16x8 af[4], bfr[4];
#pragma unroll
        for (int i = 0; i < 4; i++)
            af[i] = *(const bf16x8*)&As[(wm + i * 16 + l16) * 32 + quad * 8];
#pragma unroll
        for (int j = 0; j < 4; j++)
            bfr[j] = *(const bf16x8*)&Bs[(wn + j * 16 + l16) * 32 + quad * 8];
#pragma unroll
        for (int i = 0; i < 4; i++)
#pragma unroll
            for (int j = 0; j < 4; j++)
                acc[i][j] = __builtin_amdgcn_mfma_f32_16x16x32_bf16(af[i], bfr[j], acc[i][j], 0, 0, 0);
        __syncthreads();
    }
#pragma unroll
    for (int i = 0; i < 4; i++) {
#pragma unroll
        for (int j = 0; j < 4; j++) {
            int col = n0 + wn + j * 16 + l16;
            float bv = bias[col];
#pragma unroll
            for (int r = 0; r < 4; r++) {
                int row = m0 + wm + i * 16 + quad * 4 + r;
                stC(C + (size_t)row * N + col, acc[i][j][r] + bv);
            }
        }
    }
}

// ---------------------------------------------------------------- per-(b,h,s) rsqrt norms of q,k
__global__ __launch_bounds__(768) void rnorm_kernel(const __hip_bfloat16* __restrict__ qkv,
                                                    float* __restrict__ rq,
                                                    float* __restrict__ rk) {
    const int row = blockIdx.x;            // b*S + s
    const int w = threadIdx.x >> 6, lane = threadIdx.x & 63;
    const int b = row >> 12, s = row & 4095;
    size_t base = (size_t)row * 2304 + w * 64 + lane;
    float qv = __bfloat162float(qkv[base]);
    float kv = __bfloat162float(qkv[base + 768]);
    float sq = qv * qv, sk = kv * kv;
#pragma unroll
    for (int o = 32; o > 0; o >>= 1) {
        sq += __shfl_xor(sq, o, 64);
        sk += __shfl_xor(sk, o, 64);
    }
    if (lane == 0) {
        size_t idx = ((size_t)b * 12 + w) * 4096 + s;
        rq[idx] = rsqrtf(sq);
        rk[idx] = rsqrtf(sk);
    }
}

// ---------------------------------------------------------------- kv partials: kvpart[bh*4+chunk][e][f] = sum_s khat[s,e]*v[s,f]
__global__ __launch_bounds__(256) void kv_kernel(const __hip_bfloat16* __restrict__ qkv,
                                                 const float* __restrict__ rk,
                                                 float* __restrict__ kvpart) {
    const int bh = blockIdx.x >> 2, chunk = blockIdx.x & 3;
    const int b = bh / 12, h = bh % 12;
    const int t = threadIdx.x, wave = t >> 6, lane = t & 63;
    __shared__ __align__(16) float kt[64 * 64];
    __shared__ __align__(16) float vt[64 * 64];
    const int e0 = (lane >> 3) * 8, f0 = (lane & 7) * 8;
    float acc[8][8] = {};

    for (int tile = 0; tile < 16; tile++) {
        int sbase = chunk * 1024 + tile * 64;
        __syncthreads();
#pragma unroll
        for (int i = 0; i < 16; i++) {
            int idx = t + i * 256;
            int r = idx >> 6, c = idx & 63;
            size_t g = (size_t)(b * 4096 + sbase + r) * 2304 + 768 + h * 64 + c;
            kt[idx] = __bfloat162float(qkv[g]) * rk[(size_t)bh * 4096 + sbase + r];
            vt[idx] = __bfloat162float(qkv[g + 768]);
        }
        __syncthreads();
        // wave covers ds = wave*16 .. +16 of this tile
#pragma unroll
        for (int dsi = 0; dsi < 16; dsi++) {
            int ds = wave * 16 + dsi;
            f32x4 ka = *(f32x4*)&kt[ds * 64 + e0], kb = *(f32x4*)&kt[ds * 64 + e0 + 4];
            f32x4 va = *(f32x4*)&vt[ds * 64 + f0], vb = *(f32x4*)&vt[ds * 64 + f0 + 4];
            float ke[8] = {ka.x, ka.y, ka.z, ka.w, kb.x, kb.y, kb.z, kb.w};
            float vf[8] = {va.x, va.y, va.z, va.w, vb.x, vb.y, vb.z, vb.w};
#pragma unroll
            for (int i = 0; i < 8; i++)
#pragma unroll
                for (int j = 0; j < 8; j++) acc[i][j] += ke[i] * vf[j];
        }
    }
    // cross-wave reduce into kt, then store
    __syncthreads();
    float* red = kt;
    for (int w = 0; w < 4; w++) {
        if (wave == w) {
#pragma unroll
            for (int i = 0; i < 8; i++)
#pragma unroll
                for (int j = 0; j < 8; j++) {
                    int idx = (e0 + i) * 64 + f0 + j;
                    if (w == 0) red[idx] = acc[i][j];
                    else        red[idx] += acc[i][j];
                }
        }
        __syncthreads();
    }
    float* outp = kvpart + (size_t)blockIdx.x * 4096;
#pragma unroll
    for (int i = 0; i < 16; i++) outp[t + i * 256] = red[t + i * 256];
}

// ---------------------------------------------------------------- attention epilogue: out = norm(0.5v + (1/pi) qhat@kv) + dconv(v), bf16
__global__ __launch_bounds__(256) void attn_kernel(const __hip_bfloat16* __restrict__ qkv,
                                                   const float* __restrict__ rq,
                                                   const float* __restrict__ kvpart,
                                                   const float* __restrict__ wdconv,
                                                   __hip_bfloat16* __restrict__ outpre) {
    const int blk = blockIdx.x;            // bh*16 + sc
    const int bh = blk >> 4, sc = blk & 15;
    const int b = bh / 12, h = bh % 12;
    const int t = threadIdx.x, wave = t >> 6, lane = t & 63;
    __shared__ __align__(16) float kvL[4096];
    __shared__ float wcs[9];
    if (t < 9) wcs[t] = wdconv[h * 9 + t];
    const float* p0 = kvpart + (size_t)(bh * 4) * 4096;
#pragma unroll
    for (int i = 0; i < 16; i++) {
        int idx = t + i * 256;
        kvL[idx] = p0[idx] + p0[4096 + idx] + p0[8192 + idx] + p0[12288 + idx];
    }
    __syncthreads();
    float wc[9];
#pragma unroll
    for (int j = 0; j < 9; j++) wc[j] = wcs[j];

    for (int si = 0; si < 64; si++) {
        int s = sc * 256 + wave * 64 + si;
        size_t base = (size_t)(b * 4096 + s) * 2304 + h * 64 + lane;
        float qv = __bfloat162float(qkv[base]) * rq[(size_t)bh * 4096 + s];
        float vv = __bfloat162float(qkv[base + 1536]);
        float acc = 0.f;
#pragma unroll
        for (int e = 0; e < 64; e++)
            acc += __shfl(qv, e, 64) * kvL[e * 64 + lane];
        float o = 0.5f * vv + 0.3183098861837907f * acc;
        float ss = o * o;
#pragma unroll
        for (int ofs = 32; ofs > 0; ofs >>= 1) ss += __shfl_xor(ss, ofs, 64);
        o *= rsqrtf(ss);
        float cc = 0.f;
#pragma unroll
        for (int j = 0; j < 9; j++) {
            int s2 = s + j - 4;
            float val = ((unsigned)s2 < 4096u)
                ? __bfloat162float(qkv[(size_t)(b * 4096 + s2) * 2304 + 1536 + h * 64 + lane])
                : 0.f;
            cc += val * wc[j];
        }
        o += cc;
        outpre[(size_t)(b * 4096 + s) * 768 + h * 64 + lane] = __float2bfloat16(o);
    }
}

// ---------------------------------------------------------------- launch
extern "C" void kernel_launch(void* const* d_in, const int* in_sizes, int n_in,
                              void* d_out, int out_size, void* d_ws, size_t ws_size,
                              hipStream_t stream) {
    const float* x      = (const float*)d_in[0];
    const float* w_qkv  = (const float*)d_in[1];
    const float* b_qkv  = (const float*)d_in[2];
    const float* w_proj = (const float*)d_in[3];
    const float* b_proj = (const float*)d_in[4];
    const float* w_dc   = (const float*)d_in[5];
    float* out = (float*)d_out;

    char* ws = (char*)d_ws;
    // layout (bytes):
    __hip_bfloat16* xb     = (__hip_bfloat16*)(ws + 0);             // 100,663,296 (reused as outpreb)
    __hip_bfloat16* wqkvb  = (__hip_bfloat16*)(ws + 100663296);     //   3,538,944
    __hip_bfloat16* wprojb = (__hip_bfloat16*)(ws + 104202240);     //   1,179,648
    __hip_bfloat16* qkvb   = (__hip_bfloat16*)(ws + 105381888);     // 301,989,888
    float* rq              = (float*)(ws + 407371776);              //   3,145,728
    float* rk              = (float*)(ws + 410517504);              //   3,145,728
    float* kvpart          = (float*)(ws + 413663232);              //  12,582,912
    __hip_bfloat16* outpreb = xb;  // x dead after GEMM1

    const int NX = 16 * 4096 * 768;        // 50,331,648
    const int NWQ = 2304 * 768;            //  1,769,472
    const int NWP = 768 * 768;             //    589,824

    cvt_bf16<<<NX / 1024, 256, 0, stream>>>(x, (unsigned short*)xb, NX);
    cvt_bf16<<<NWQ / 1024, 256, 0, stream>>>(w_qkv, (unsigned short*)wqkvb, NWQ);
    cvt_bf16<<<NWP / 1024, 256, 0, stream>>>(w_proj, (unsigned short*)wprojb, NWP);

    gemm_bt<__hip_bfloat16><<<dim3(2304 / 128, 65536 / 128), 256, 0, stream>>>(
        xb, wqkvb, b_qkv, qkvb, 65536, 2304, 768);

    rnorm_kernel<<<65536, 768, 0, stream>>>(qkvb, rq, rk);

    kv_kernel<<<192 * 4, 256, 0, stream>>>(qkvb, rk, kvpart);

    attn_kernel<<<192 * 16, 256, 0, stream>>>(qkvb, rq, kvpart, w_dc, outpreb);

    gemm_bt<float><<<dim3(768 / 128, 65536 / 128), 256, 0, stream>>>(
        outpreb, wprojb, b_proj, out, 65536, 768, 768);
}

// Round 2
// 981.769 us; speedup vs baseline: 2.1950x; 2.1950x over previous
//
#include <hip/hip_runtime.h>
#include <hip/hip_bf16.h>

#define DEV __device__ __forceinline__

typedef __attribute__((ext_vector_type(8))) short bf16x8;
typedef __attribute__((ext_vector_type(4))) float f32x4;

// ---------------------------------------------------------------- helpers
DEV unsigned short bfbits(float x) {
    __hip_bfloat16 b = __float2bfloat16(x);
    return __builtin_bit_cast(unsigned short, b);
}
DEV float b2f(unsigned short u) {
    __hip_bfloat16 b = __builtin_bit_cast(__hip_bfloat16, u);
    return __bfloat162float(b);
}

DEV void gl2lds16(const void* g, void* l) {
    __builtin_amdgcn_global_load_lds(
        (const __attribute__((address_space(1))) void*)g,
        (__attribute__((address_space(3))) void*)l,
        16, 0, 0);
}

DEV void stC(float* p, float v) { *p = v; }
DEV void stC(__hip_bfloat16* p, float v) { *p = __float2bfloat16(v); }

// ---------------------------------------------------------------- fp32 -> bf16 convert
__global__ __launch_bounds__(256) void cvt_bf16(const float* __restrict__ in,
                                                unsigned short* __restrict__ out, int n) {
    int i = (blockIdx.x * 256 + threadIdx.x) * 4;
    if (i >= n) return;
    float4 f = *(const float4*)(in + i);
    ushort4 u;
    u.x = bfbits(f.x); u.y = bfbits(f.y); u.z = bfbits(f.z); u.w = bfbits(f.w);
    *(ushort4*)(out + i) = u;
}

// ---------------------------------------------------------------- generic bf16 GEMM: C = A @ B^T + bias  (m97 structure)
template <typename OutT>
__global__ __launch_bounds__(256) void gemm_bt(const __hip_bfloat16* __restrict__ A,
                                               const __hip_bfloat16* __restrict__ B,
                                               const float* __restrict__ bias,
                                               OutT* __restrict__ C,
                                               int M, int N, int K) {
    __shared__ __align__(16) unsigned short As[128 * 32];
    __shared__ __align__(16) unsigned short Bs[128 * 32];
    const int t = threadIdx.x;
    const int wave = t >> 6, lane = t & 63;
    const int quad = lane >> 4, l16 = lane & 15;
    const int m0 = blockIdx.y * 128, n0 = blockIdx.x * 128;
    const int wm = (wave & 1) * 64, wn = (wave >> 1) * 64;
    const int r0 = t >> 2;
    const int c0 = (t & 3) * 8;
    const unsigned short* Au = (const unsigned short*)A;
    const unsigned short* Bu = (const unsigned short*)B;

    f32x4 acc[4][4] = {};
    for (int k0 = 0; k0 < K; k0 += 32) {
        gl2lds16(Au + (size_t)(m0 + r0) * K + k0 + c0,      As + t * 8);
        gl2lds16(Au + (size_t)(m0 + 64 + r0) * K + k0 + c0, As + 2048 + t * 8);
        gl2lds16(Bu + (size_t)(n0 + r0) * K + k0 + c0,      Bs + t * 8);
        gl2lds16(Bu + (size_t)(n0 + 64 + r0) * K + k0 + c0, Bs + 2048 + t * 8);
        __syncthreads();
        bf16x8 af[4], bfr[4];
#pragma unroll
        for (int i = 0; i < 4; i++)
            af[i] = *(const bf16x8*)&As[(wm + i * 16 + l16) * 32 + quad * 8];
#pragma unroll
        for (int j = 0; j < 4; j++)
            bfr[j] = *(const bf16x8*)&Bs[(wn + j * 16 + l16) * 32 + quad * 8];
#pragma unroll
        for (int i = 0; i < 4; i++)
#pragma unroll
            for (int j = 0; j < 4; j++)
                acc[i][j] = __builtin_amdgcn_mfma_f32_16x16x32_bf16(af[i], bfr[j], acc[i][j], 0, 0, 0);
        __syncthreads();
    }
#pragma unroll
    for (int i = 0; i < 4; i++) {
#pragma unroll
        for (int j = 0; j < 4; j++) {
            int col = n0 + wn + j * 16 + l16;
            float bv = bias[col];
#pragma unroll
            for (int r = 0; r < 4; r++) {
                int row = m0 + wm + i * 16 + quad * 4 + r;
                stC(C + (size_t)row * N + col, acc[i][j][r] + bv);
            }
        }
    }
}

// ---------------------------------------------------------------- GEMM1 with fused bias + q/k row-norm epilogue
// Writes qhat/khat/v as bf16 head-major [b,h,s,d]. N=2304 fixed, K=768 fixed.
__global__ __launch_bounds__(256) void gemm_qkv(const __hip_bfloat16* __restrict__ A,
                                                const __hip_bfloat16* __restrict__ B,
                                                const float* __restrict__ bias,
                                                unsigned short* __restrict__ qhat,
                                                unsigned short* __restrict__ khat,
                                                unsigned short* __restrict__ varr) {
    const int K = 768, NN = 2304;
    __shared__ __align__(16) unsigned short As[128 * 32];
    __shared__ __align__(16) unsigned short Bs[128 * 32];
    const int t = threadIdx.x;
    const int wave = t >> 6, lane = t & 63;
    const int quad = lane >> 4, l16 = lane & 15;
    const int m0 = blockIdx.y * 128, n0 = blockIdx.x * 128;
    const int wm = (wave & 1) * 64, wn = (wave >> 1) * 64;
    const int r0 = t >> 2;
    const int c0 = (t & 3) * 8;
    const unsigned short* Au = (const unsigned short*)A;
    const unsigned short* Bu = (const unsigned short*)B;

    f32x4 acc[4][4] = {};
    for (int k0 = 0; k0 < K; k0 += 32) {
        gl2lds16(Au + (size_t)(m0 + r0) * K + k0 + c0,      As + t * 8);
        gl2lds16(Au + (size_t)(m0 + 64 + r0) * K + k0 + c0, As + 2048 + t * 8);
        gl2lds16(Bu + (size_t)(n0 + r0) * K + k0 + c0,      Bs + t * 8);
        gl2lds16(Bu + (size_t)(n0 + 64 + r0) * K + k0 + c0, Bs + 2048 + t * 8);
        __syncthreads();
        bf16x8 af[4], bfr[4];
#pragma unroll
        for (int i = 0; i < 4; i++)
            af[i] = *(const bf16x8*)&As[(wm + i * 16 + l16) * 32 + quad * 8];
#pragma unroll
        for (int j = 0; j < 4; j++)
            bfr[j] = *(const bf16x8*)&Bs[(wn + j * 16 + l16) * 32 + quad * 8];
#pragma unroll
        for (int i = 0; i < 4; i++)
#pragma unroll
            for (int j = 0; j < 4; j++)
                acc[i][j] = __builtin_amdgcn_mfma_f32_16x16x32_bf16(af[i], bfr[j], acc[i][j], 0, 0, 0);
        __syncthreads();
    }

    // epilogue: bias -> (q,k: row-norm) -> bf16 head-major store
    const int colbase = n0 + wn;               // multiple of 64
    const int sec = colbase / 768;             // 0=q 1=k 2=v (tile never straddles)
    const int cin = colbase - sec * 768;
    const int h = cin >> 6;                    // head, uniform per wave
    const int b = m0 >> 12;                    // batch, uniform per block
    unsigned short* dst = (sec == 0) ? qhat : (sec == 1) ? khat : varr;
    float bv[4];
#pragma unroll
    for (int j = 0; j < 4; j++) bv[j] = bias[colbase + j * 16 + l16];

    const size_t headbase = (size_t)(b * 12 + h) * 4096;
#pragma unroll
    for (int i = 0; i < 4; i++) {
        float o[4][4];
#pragma unroll
        for (int j = 0; j < 4; j++)
#pragma unroll
            for (int r = 0; r < 4; r++) o[j][r] = acc[i][j][r] + bv[j];
        if (sec < 2) {
#pragma unroll
            for (int r = 0; r < 4; r++) {
                float ss = o[0][r]*o[0][r] + o[1][r]*o[1][r] + o[2][r]*o[2][r] + o[3][r]*o[3][r];
                ss += __shfl_xor(ss, 1, 64);
                ss += __shfl_xor(ss, 2, 64);
                ss += __shfl_xor(ss, 4, 64);
                ss += __shfl_xor(ss, 8, 64);
                float sc = rsqrtf(ss);
#pragma unroll
                for (int j = 0; j < 4; j++) o[j][r] *= sc;
            }
        }
#pragma unroll
        for (int j = 0; j < 4; j++)
#pragma unroll
            for (int r = 0; r < 4; r++) {
                int s = (m0 + wm + i * 16 + quad * 4 + r) & 4095;
                dst[(headbase + s) * 64 + j * 16 + l16] = bfbits(o[j][r]);
            }
    }
}

// ---------------------------------------------------------------- kv partials: kvpart[bh*4+chunk][e][f] = sum_s khat[s,e]*v[s,f]
__global__ __launch_bounds__(256) void kv_kernel(const unsigned short* __restrict__ khat,
                                                 const unsigned short* __restrict__ varr,
                                                 float* __restrict__ kvpart) {
    const int bh = blockIdx.x >> 2, chunk = blockIdx.x & 3;
    const int t = threadIdx.x, wave = t >> 6, lane = t & 63;
    __shared__ __align__(16) float kt[64 * 64];
    __shared__ __align__(16) float vt[64 * 64];
    const int e0 = (lane >> 3) * 8, f0 = (lane & 7) * 8;
    float acc[8][8] = {};

    for (int tile = 0; tile < 16; tile++) {
        int sbase = chunk * 1024 + tile * 64;
        __syncthreads();
#pragma unroll
        for (int i = 0; i < 2; i++) {
            int c = t + i * 256;                  // 0..511 chunk of 8 elems
            int row = c >> 3, off = (c & 7) * 8;
            size_t g = ((size_t)bh * 4096 + sbase + row) * 64 + off;
            bf16x8 kk = *(const bf16x8*)(khat + g);
            bf16x8 vv = *(const bf16x8*)(varr + g);
#pragma unroll
            for (int j = 0; j < 8; j++) {
                kt[row * 64 + off + j] = b2f((unsigned short)kk[j]);
                vt[row * 64 + off + j] = b2f((unsigned short)vv[j]);
            }
        }
        __syncthreads();
#pragma unroll
        for (int dsi = 0; dsi < 16; dsi++) {
            int ds = wave * 16 + dsi;
            f32x4 ka = *(f32x4*)&kt[ds * 64 + e0], kb = *(f32x4*)&kt[ds * 64 + e0 + 4];
            f32x4 va = *(f32x4*)&vt[ds * 64 + f0], vb = *(f32x4*)&vt[ds * 64 + f0 + 4];
            float ke[8] = {ka.x, ka.y, ka.z, ka.w, kb.x, kb.y, kb.z, kb.w};
            float vf[8] = {va.x, va.y, va.z, va.w, vb.x, vb.y, vb.z, vb.w};
#pragma unroll
            for (int i = 0; i < 8; i++)
#pragma unroll
                for (int j = 0; j < 8; j++) acc[i][j] += ke[i] * vf[j];
        }
    }
    __syncthreads();
    float* red = kt;
    for (int w = 0; w < 4; w++) {
        if (wave == w) {
#pragma unroll
            for (int i = 0; i < 8; i++)
#pragma unroll
                for (int j = 0; j < 8; j++) {
                    int idx = (e0 + i) * 64 + f0 + j;
                    if (w == 0) red[idx] = acc[i][j];
                    else        red[idx] += acc[i][j];
                }
        }
        __syncthreads();
    }
    float* outp = kvpart + (size_t)blockIdx.x * 4096;
#pragma unroll
    for (int i = 0; i < 16; i++) outp[t + i * 256] = red[t + i * 256];
}

// ---------------------------------------------------------------- reduce partials -> bf16 kvT[bh][f][e]
__global__ __launch_bounds__(256) void kvred_kernel(const float* __restrict__ kvpart,
                                                    unsigned short* __restrict__ kvT) {
    const int bh = blockIdx.x;
    const int t = threadIdx.x;
    __shared__ float kvf[64 * 65];
    const float* p0 = kvpart + (size_t)(bh * 4) * 4096;
#pragma unroll
    for (int i = 0; i < 16; i++) {
        int idx = t + i * 256;                 // e*64+f
        int e = idx >> 6, f = idx & 63;
        kvf[e * 65 + f] = p0[idx] + p0[4096 + idx] + p0[8192 + idx] + p0[12288 + idx];
    }
    __syncthreads();
#pragma unroll
    for (int i = 0; i < 16; i++) {
        int o = t + i * 256;                   // f*64+e
        int f = o >> 6, e = o & 63;
        kvT[(size_t)bh * 4096 + o] = bfbits(kvf[e * 65 + f]);
    }
}

// ---------------------------------------------------------------- attention: out = norm(0.5v + (1/pi) qhat@kv) + dconv(v)
// MFMA over [128 s x 64 f], K=64. A (qhat) and B (kvT) fragments straight from global.
__global__ __launch_bounds__(256) void attn_kernel(const unsigned short* __restrict__ qhat,
                                                   const unsigned short* __restrict__ varr,
                                                   const unsigned short* __restrict__ kvT,
                                                   const float* __restrict__ wdconv,
                                                   __hip_bfloat16* __restrict__ outpre) {
    const int st = blockIdx.x;                 // 0..31
    const int bh = blockIdx.y;                 // 0..191
    const int b = bh / 12, h = bh % 12;
    const int s0 = st * 128;
    const int t = threadIdx.x, w = t >> 6, lane = t & 63;
    const int quad = lane >> 4, l16 = lane & 15;

    __shared__ __align__(16) unsigned short vt[136 * 64];  // rows s0-4 .. s0+131
    __shared__ float oL[128 * 65];

    // stage v tile with halo (zero OOB)
    const size_t vb = (size_t)bh * 4096;
#pragma unroll
    for (int i = 0; i < 5; i++) {
        int c = t + i * 256;                   // chunk of 8 elems; 1088 total
        if (c < 1088) {
            int row = c >> 3, off = (c & 7) * 8;
            int gs = s0 - 4 + row;
            bf16x8 vv = {};
            if ((unsigned)gs < 4096u) vv = *(const bf16x8*)(varr + (vb + gs) * 64 + off);
            *(bf16x8*)&vt[row * 64 + off] = vv;
        }
    }

    // B fragments from kvT (global): B[n=l16+j*16][k=kstep*32+quad*8+..]
    bf16x8 bfr[2][4];
#pragma unroll
    for (int ks = 0; ks < 2; ks++)
#pragma unroll
        for (int j = 0; j < 4; j++)
            bfr[ks][j] = *(const bf16x8*)(kvT + (size_t)bh * 4096 + (j * 16 + l16) * 64 + ks * 32 + quad * 8);

    // MFMA: rows w*32 + i*16
    f32x4 acc[2][4] = {};
#pragma unroll
    for (int i = 0; i < 2; i++) {
#pragma unroll
        for (int ks = 0; ks < 2; ks++) {
            bf16x8 af = *(const bf16x8*)(qhat + (vb + s0 + w * 32 + i * 16 + l16) * 64 + ks * 32 + quad * 8);
#pragma unroll
            for (int j = 0; j < 4; j++)
                acc[i][j] = __builtin_amdgcn_mfma_f32_16x16x32_bf16(af, bfr[ks][j], acc[i][j], 0, 0, 0);
        }
    }
    __syncthreads();

    // epilogue 1: o = 0.5 v + (1/pi) attn; row-norm; write oL
    const float inv_pi = 0.3183098861837907f;
#pragma unroll
    for (int i = 0; i < 2; i++) {
        float o[4][4];
#pragma unroll
        for (int r = 0; r < 4; r++) {
            int rl = w * 32 + i * 16 + quad * 4 + r;
#pragma unroll
            for (int j = 0; j < 4; j++) {
                float vval = b2f(vt[(rl + 4) * 64 + j * 16 + l16]);
                o[j][r] = 0.5f * vval + inv_pi * acc[i][j][r];
            }
            float ss = o[0][r]*o[0][r] + o[1][r]*o[1][r] + o[2][r]*o[2][r] + o[3][r]*o[3][r];
            ss += __shfl_xor(ss, 1, 64);
            ss += __shfl_xor(ss, 2, 64);
            ss += __shfl_xor(ss, 4, 64);
            ss += __shfl_xor(ss, 8, 64);
            float sc = rsqrtf(ss);
#pragma unroll
            for (int j = 0; j < 4; j++)
                oL[rl * 65 + j * 16 + l16] = o[j][r] * sc;
        }
    }
    __syncthreads();

    // epilogue 2: + depthwise conv, store bf16 row-major [b,s,768]
    float wc[9];
#pragma unroll
    for (int j = 0; j < 9; j++) wc[j] = wdconv[h * 9 + j];
#pragma unroll
    for (int i = 0; i < 32; i++) {
        int c = t + i * 256;                   // s_local*64 + f
        int sl = c >> 6, f = c & 63;
        float cc = 0.f;
#pragma unroll
        for (int j = 0; j < 9; j++) cc += wc[j] * b2f(vt[(sl + j) * 64 + f]);
        float oo = oL[sl * 65 + f] + cc;
        outpre[(size_t)(b * 4096 + s0 + sl) * 768 + h * 64 + f] = __float2bfloat16(oo);
    }
}

// ---------------------------------------------------------------- launch
extern "C" void kernel_launch(void* const* d_in, const int* in_sizes, int n_in,
                              void* d_out, int out_size, void* d_ws, size_t ws_size,
                              hipStream_t stream) {
    const float* x      = (const float*)d_in[0];
    const float* w_qkv  = (const float*)d_in[1];
    const float* b_qkv  = (const float*)d_in[2];
    const float* w_proj = (const float*)d_in[3];
    const float* b_proj = (const float*)d_in[4];
    const float* w_dc   = (const float*)d_in[5];
    float* out = (float*)d_out;

    char* ws = (char*)d_ws;
    __hip_bfloat16* xb      = (__hip_bfloat16*)(ws + 0);             // 100,663,296 (reused as outpre)
    __hip_bfloat16* wqkvb   = (__hip_bfloat16*)(ws + 100663296);     //   3,538,944
    __hip_bfloat16* wprojb  = (__hip_bfloat16*)(ws + 104202240);     //   1,179,648
    unsigned short* qhat    = (unsigned short*)(ws + 105381888);     // 100,663,296
    unsigned short* khat    = (unsigned short*)(ws + 206045184);     // 100,663,296
    unsigned short* varr    = (unsigned short*)(ws + 306708480);     // 100,663,296
    float* kvpart           = (float*)(ws + 407371776);              //  12,582,912
    unsigned short* kvT     = (unsigned short*)(ws + 419954688);     //   1,572,864
    __hip_bfloat16* outpreb = xb;  // x dead after GEMM1

    const int NX = 16 * 4096 * 768;
    const int NWQ = 2304 * 768;
    const int NWP = 768 * 768;

    cvt_bf16<<<NX / 1024, 256, 0, stream>>>(x, (unsigned short*)xb, NX);
    cvt_bf16<<<NWQ / 1024, 256, 0, stream>>>(w_qkv, (unsigned short*)wqkvb, NWQ);
    cvt_bf16<<<NWP / 1024, 256, 0, stream>>>(w_proj, (unsigned short*)wprojb, NWP);

    gemm_qkv<<<dim3(2304 / 128, 65536 / 128), 256, 0, stream>>>(
        xb, wqkvb, b_qkv, qhat, khat, varr);

    kv_kernel<<<192 * 4, 256, 0, stream>>>(khat, varr, kvpart);

    kvred_kernel<<<192, 256, 0, stream>>>(kvpart, kvT);

    attn_kernel<<<dim3(32, 192), 256, 0, stream>>>(qhat, varr, kvT, w_dc, (__hip_bfloat16*)xb);

    gemm_bt<float><<<dim3(768 / 128, 65536 / 128), 256, 0, stream>>>(
        (__hip_bfloat16*)xb, wprojb, b_proj, out, 65536, 768, 768);
}